// Round 7
// baseline (81.657 us; speedup 1.0000x reference)
//
#include <hip/hip_runtime.h>

// Problem constants (match reference)
#define BATCH 256
#define PTS   4096
#define HH    512
#define WW    512

#define ROWS_PER_TILE 32
#define TILES (HH / ROWS_PER_TILE)        // 16 tiles per batch
#define TILE_ELEMS (ROWS_PER_TILE * WW)   // 16384 floats = 64 KB output
#define TILE_VEC4 (TILE_ELEMS / 4)        // 4096 float4

typedef float f32x4 __attribute__((ext_vector_type(4)));

// Fill-shaped scatter: each block owns one 32x512 tile of one batch.
// Phase 1: zero the tile with dependency-free register stores (no LDS,
// no loads -> stores issue immediately, like the rocclr fill that hits
// 6.9 TB/s). Phase 2 (after __syncthreads drains vmcnt(0), ordering the
// zeros at L2): scan the batch's valid points and atomicAdd the ~256
// hits directly -- target lines are L2-dirty, so the RMW is an L2 hit.
// Tiles partition the output, so no cross-block ordering is needed.
__global__ __launch_bounds__(256) void zero_scatter_kernel(
        const int* __restrict__ indices,      // [B, P, 2] int32
        const int* __restrict__ num_valid,    // [B] int32
        const float* __restrict__ feats,      // [B, P, 1] f32
        float* __restrict__ out)              // [B, H, W] f32
{
    // XCD-aware remap: each XCD owns 32 whole batches (all 16 tiles), so
    // a batch's 48 KB of indices+feats is fetched into ONE L2.
    int i = blockIdx.x;                       // [0, 4096)
    int xcd  = i & 7;
    int slot = i >> 3;                        // [0, 512)
    int b = xcd * (BATCH / 8) + (slot >> 4);  // 32 batches per XCD
    int t = slot & (TILES - 1);
    int tidx = threadIdx.x;

    // Phase 1: dependency-free zero burst. 16 dwordx4 stores/thread,
    // each wave-instruction covers 4 KB contiguous.
    float* ob = out + (size_t)b * (HH * WW) + (size_t)t * TILE_ELEMS;
    f32x4* dst = reinterpret_cast<f32x4*>(ob);
    f32x4 z = {0.f, 0.f, 0.f, 0.f};
    #pragma unroll
    for (int k = 0; k < TILE_VEC4 / 256; ++k)
        dst[k * 256 + tidx] = z;

    int nv = num_valid[b];                    // overlaps store drain

    // __syncthreads emits s_waitcnt vmcnt(0) before s_barrier: all this
    // block's zero-stores are committed at L2 before any atomic below.
    __syncthreads();

    // Phase 2: scan valid prefix (2 points per int4 + one float2 feats
    // load, L2-resident across the 16 blocks sharing this batch).
    int r0 = t * ROWS_PER_TILE;
    const int4*   idx4 = reinterpret_cast<const int4*>(indices) + (size_t)b * (PTS / 2);
    const float2* fb2  = reinterpret_cast<const float2*>(feats) + (size_t)b * (PTS / 2);
    int n4 = (nv + 1) >> 1;
    for (int q = tidx; q < n4; q += 256) {
        int4 two = idx4[q];                   // points 2q (x,y), 2q+1 (z,w)
        float2 v = fb2[q];
        int ra = two.x - r0;
        if ((unsigned)ra < ROWS_PER_TILE)
            atomicAdd(ob + (size_t)ra * WW + two.y, v.x);
        int rb = two.z - r0;
        if ((2 * q + 1) < nv && (unsigned)rb < ROWS_PER_TILE)
            atomicAdd(ob + (size_t)rb * WW + two.w, v.y);
    }
}

extern "C" void kernel_launch(void* const* d_in, const int* in_sizes, int n_in,
                              void* d_out, int out_size, void* d_ws, size_t ws_size,
                              hipStream_t stream) {
    const int*   indices   = (const int*)d_in[0];
    const int*   num_valid = (const int*)d_in[1];
    const float* feats     = (const float*)d_in[2];
    float*       out       = (float*)d_out;

    zero_scatter_kernel<<<BATCH * TILES, 256, 0, stream>>>(indices, num_valid, feats, out);
}

// Round 8
// 80.387 us; speedup vs baseline: 1.0158x; 1.0158x over previous
//
#include <hip/hip_runtime.h>

// Problem constants (match reference)
#define BATCH 256
#define PTS   4096
#define HH    512
#define WW    512

#define ROWS_PER_TILE 16
#define TILES (HH / ROWS_PER_TILE)       // 32 tiles per batch
#define TILE_ELEMS (ROWS_PER_TILE * WW)  // 8192 floats = 32 KB LDS

typedef float f32x4 __attribute__((ext_vector_type(4)));

// Round-4 structure (best: 50.9 us), ONE change: plain dwordx4 stores
// instead of __builtin_nontemporal_store. Hypothesis: the NT path
// (L2-bypass) caps at ~5.5 TB/s while the plain-store dirty-eviction
// path is what the rocclr fill rides to 6.9 TB/s. Output lines are
// written once and never re-read, so correctness is unaffected.
__global__ __launch_bounds__(256) void tile_gather_kernel(
        const int* __restrict__ indices,      // [B, P, 2] int32
        const int* __restrict__ num_valid,    // [B] int32
        const float* __restrict__ feats,      // [B, P, 1] f32
        float* __restrict__ out)              // [B, H, W] f32
{
    __shared__ float tile[TILE_ELEMS];

    // XCD-aware remap: each XCD owns 32 whole batches (all 32 tiles):
    // the batch's 32 KB index list + 16 KB feats stay in ONE L2.
    int i = blockIdx.x;                       // [0, 8192)
    int xcd  = i & 7;
    int slot = i >> 3;                        // [0, 1024)
    int b = xcd * (BATCH / 8) + (slot >> 5);  // 32 batches per XCD
    int t = slot & (TILES - 1);
    int r0 = t * ROWS_PER_TILE;
    int tidx = threadIdx.x;

    // Zero the LDS tile, vectorized (ds_write_b128): 8 stores/thread.
    f32x4* tile4 = reinterpret_cast<f32x4*>(tile);
    #pragma unroll
    for (int k = tidx; k < TILE_ELEMS / 4; k += 256)
        tile4[k] = (f32x4){0.f, 0.f, 0.f, 0.f};

    int nv = num_valid[b];                    // block-uniform
    __syncthreads();

    // Scan the valid prefix: 2 points per int4 load + one float2 feats
    // load (adjacent points' features are contiguous). L2-resident.
    const int4*   idx4 = reinterpret_cast<const int4*>(indices) + (size_t)b * (PTS / 2);
    const float2* fb2  = reinterpret_cast<const float2*>(feats) + (size_t)b * (PTS / 2);

    int n4 = (nv + 1) >> 1;                   // pairs to visit
    for (int q = tidx; q < n4; q += 256) {
        int4 two = idx4[q];                   // points 2q (x,y), 2q+1 (z,w)
        float2 v = fb2[q];
        int ra = two.x - r0;
        if ((unsigned)ra < ROWS_PER_TILE)
            atomicAdd(&tile[ra * WW + two.y], v.x);
        int rb = two.z - r0;
        if ((2 * q + 1) < nv && (unsigned)rb < ROWS_PER_TILE)
            atomicAdd(&tile[rb * WW + two.w], v.y);
    }
    __syncthreads();

    // Write the tile exactly once: 2048 plain float4 stores, 8/thread.
    // Dirty lines aggregate in L2 and stream out via eviction — the
    // same path the 6.9 TB/s rocclr fill uses.
    float* ob = out + (size_t)b * (HH * WW) + (size_t)r0 * WW;
    f32x4* dst = reinterpret_cast<f32x4*>(ob);
    #pragma unroll
    for (int k = tidx; k < TILE_ELEMS / 4; k += 256)
        dst[k] = tile4[k];
}

extern "C" void kernel_launch(void* const* d_in, const int* in_sizes, int n_in,
                              void* d_out, int out_size, void* d_ws, size_t ws_size,
                              hipStream_t stream) {
    const int*   indices   = (const int*)d_in[0];
    const int*   num_valid = (const int*)d_in[1];
    const float* feats     = (const float*)d_in[2];
    float*       out       = (float*)d_out;

    tile_gather_kernel<<<BATCH * TILES, 256, 0, stream>>>(indices, num_valid, feats, out);
}

// Round 9
// 50.147 us; speedup vs baseline: 1.6284x; 1.6030x over previous
//
#include <hip/hip_runtime.h>

// Problem constants (match reference)
#define BATCH 256
#define PTS   4096
#define HH    512
#define WW    512

#define ROWS_PER_TILE 16
#define TILES (HH / ROWS_PER_TILE)       // 32 tiles per batch
#define TILE_ELEMS (ROWS_PER_TILE * WW)  // 8192 floats = 32 KB LDS

typedef float f32x4 __attribute__((ext_vector_type(4)));

// ws layout:
//   entries: BATCH*PTS uint2 (packed pos, val bits)  = 8 MB   @ ws + 0
//   counts : BATCH*TILES u32                          = 32 KB
//   offsets: BATCH*TILES u32                          = 32 KB
#define ENTRIES_BYTES ((size_t)BATCH * PTS * 8)

// Discriminating experiment: R6's binned structure, but K2 uses PLAIN
// dwordx4 stores. K2's read working set is ~1 KB/block (pre-binned
// entries) -- nothing for the store stream to thrash. If R8's collapse
// was L2-read-thrash, K2 now matches the rocclr fill shape (contiguous
// full-line plain stores, no reads) and should hit ~6.9 TB/s. If it's
// write-allocate, K2 stays slow and NT@5.5 TB/s is proven structural.

// K1: one block per batch. Scan the point list ONCE, build a per-batch
// CSR binned by 16-row tile. Batch->XCD mapping matches K2 so entries
// are produced and consumed through the same L2.
__global__ __launch_bounds__(1024) void bin_kernel(
        const int* __restrict__ indices,      // [B, P, 2] int32
        const int* __restrict__ num_valid,    // [B] int32
        const float* __restrict__ feats,      // [B, P, 1] f32
        uint2* __restrict__ entries,          // [B, P]
        unsigned* __restrict__ counts,        // [B, TILES]
        unsigned* __restrict__ offsets)       // [B, TILES]
{
    __shared__ unsigned cnt[TILES];
    __shared__ unsigned cur[TILES];

    // Same XCD ownership as K2: XCD x owns batches [x*32, x*32+32).
    int i = blockIdx.x;
    int b = (i & 7) * (BATCH / 8) + (i >> 3);
    int tidx = threadIdx.x;
    if (tidx < TILES) cnt[tidx] = 0;
    int nv = num_valid[b];
    __syncthreads();

    const int2* idx2 = reinterpret_cast<const int2*>(indices) + (size_t)b * PTS;

    // Pass A: count points per tile (32 LDS counters, one per bank).
    for (int p = tidx; p < nv; p += 1024)
        atomicAdd(&cnt[((unsigned)idx2[p].x) >> 4], 1u);
    __syncthreads();

    // Exclusive prefix over 32 elements (thread 0, negligible).
    if (tidx == 0) {
        unsigned run = 0;
        for (int k = 0; k < TILES; ++k) { cur[k] = run; run += cnt[k]; }
    }
    __syncthreads();

    if (tidx < TILES) {
        counts[b * TILES + tidx]  = cnt[tidx];
        offsets[b * TILES + tidx] = cur[tidx];
    }
    __syncthreads();   // offsets captured before pass B mutates cur[]

    // Pass B: re-scan (L1/L2-hot) and write entries at exact positions.
    const float* fb = feats + (size_t)b * PTS;
    uint2* eb = entries + (size_t)b * PTS;
    for (int p = tidx; p < nv; p += 1024) {
        int2 ij = idx2[p];
        float v = fb[p];
        unsigned bin = ((unsigned)ij.x) >> 4;
        unsigned pos = atomicAdd(&cur[bin], 1u);   // absolute within batch
        eb[pos] = make_uint2((unsigned)((ij.x & (ROWS_PER_TILE - 1)) * WW + ij.y),
                             __float_as_uint(v));
    }
}

// K2: one block per (batch, tile). Zero 32 KB LDS, apply ~128 binned
// entries (1 KB contiguous read), write the tile once with PLAIN
// dwordx4 stores (dirty-eviction path).
__global__ __launch_bounds__(256) void tile_write_kernel(
        const uint2* __restrict__ entries,
        const unsigned* __restrict__ counts,
        const unsigned* __restrict__ offsets,
        float* __restrict__ out)              // [B, H, W] f32
{
    __shared__ float tile[TILE_ELEMS];

    // XCD-aware remap: each XCD owns 32 whole batches.
    int i = blockIdx.x;                       // [0, 8192)
    int xcd  = i & 7;
    int slot = i >> 3;                        // [0, 1024)
    int b = xcd * (BATCH / 8) + (slot >> 5);
    int t = slot & (TILES - 1);
    int tidx = threadIdx.x;

    f32x4* tile4 = reinterpret_cast<f32x4*>(tile);
    #pragma unroll
    for (int k = tidx; k < TILE_ELEMS / 4; k += 256)
        tile4[k] = (f32x4){0.f, 0.f, 0.f, 0.f};

    unsigned n   = counts[b * TILES + t];
    unsigned off = offsets[b * TILES + t];
    __syncthreads();

    const uint2* eb = entries + (size_t)b * PTS + off;
    for (unsigned e = tidx; e < n; e += 256) {
        uint2 ent = eb[e];
        atomicAdd(&tile[ent.x], __uint_as_float(ent.y));
    }
    __syncthreads();

    // Plain stores: full-line contiguous, dirty lines aggregate in L2
    // and stream out via eviction (the rocclr-fill path).
    float* ob = out + (size_t)b * (HH * WW) + (size_t)t * TILE_ELEMS;
    f32x4* dst = reinterpret_cast<f32x4*>(ob);
    #pragma unroll
    for (int k = tidx; k < TILE_ELEMS / 4; k += 256)
        dst[k] = tile4[k];
}

extern "C" void kernel_launch(void* const* d_in, const int* in_sizes, int n_in,
                              void* d_out, int out_size, void* d_ws, size_t ws_size,
                              hipStream_t stream) {
    const int*   indices   = (const int*)d_in[0];
    const int*   num_valid = (const int*)d_in[1];
    const float* feats     = (const float*)d_in[2];
    float*       out       = (float*)d_out;

    uint2*    entries = (uint2*)d_ws;
    unsigned* counts  = (unsigned*)((char*)d_ws + ENTRIES_BYTES);
    unsigned* offsets = counts + BATCH * TILES;

    bin_kernel<<<BATCH, 1024, 0, stream>>>(indices, num_valid, feats,
                                           entries, counts, offsets);
    tile_write_kernel<<<BATCH * TILES, 256, 0, stream>>>(entries, counts,
                                                         offsets, out);
}